// Round 19
// baseline (118.777 us; speedup 1.0000x reference)
//
#include <hip/hip_runtime.h>

#define IN_    16
#define HID_   50
#define T_     128
#define NCLS_  20
#define BPB_   16     // batches per block = MFMA N
#define NTHR_  320    // 5 waves, all compute: tiles {3,3,3,2,2}
#define KP_    72     // state row stride (halves): 50 h + 1 bias + 21 pad; 36 dw = 2-way banks
#define KPW_   36
#define XT_    256    // x_all halves per timestep (16 batches x 16 feats)
#define XALL_  (T_ * XT_)        // 32768 halves = 64 KB
#define STSZ_  (BPB_ * KP_)      // 1152 halves per state buffer
#define LDSB_  ((XALL_ + 2 * STSZ_) * 2)   // dynamic LDS bytes = 70144

typedef _Float16 half8 __attribute__((ext_vector_type(8)));
typedef float    f32x4 __attribute__((ext_vector_type(4)));
typedef unsigned int u32;

#define L2E_ 1.4426950408889634f
__device__ __forceinline__ u32 pkh2(float a, float b) {
    union { u32 v; _Float16 h[2]; } p; p.h[0] = (_Float16)a; p.h[1] = (_Float16)b; return p.v;
}
#define MFMA(A, B, C) __builtin_amdgcn_mfma_f32_16x16x32_f16((A), (B), (C), 0, 0, 0)
// activation-domain helpers (weights/bias PRE-SCALED by -log2e / -2log2e)
#define SIGS(v)  __builtin_amdgcn_rcpf(1.0f + __builtin_amdgcn_exp2f(v))
#define TANHS(v) fmaf(2.0f, __builtin_amdgcn_rcpf(1.0f + __builtin_amdgcn_exp2f(v)), -1.0f)

// A-fragment slice from GLOBAL. K layout: 0..15 = x (W_ih), 16..65 = h (W_hh),
// 66 = bias row, 67..95 = zero pad.
__device__ __forceinline__ half8 load_afrag(const float* __restrict__ W_ih,
                                            const float* __restrict__ W_hh,
                                            const float* __restrict__ b_ih,
                                            const float* __restrict__ b_hh,
                                            int s, int c, int q) {
    half8 r = {};
    const int u = s >> 2, kk = s & 3;
    if (u < HID_) {
        const float sc = (kk == 2) ? (-2.0f * L2E_) : (-L2E_);
        const int g = kk * HID_ + u;
        #pragma unroll
        for (int e = 0; e < 8; ++e) {
            const int k = c * 32 + q * 8 + e;
            float w = 0.f;
            if (k < IN_)                 w = W_ih[g * IN_ + k];
            else if (k < IN_ + HID_)     w = W_hh[g * HID_ + (k - IN_)];
            else if (k == IN_ + HID_)    w = b_ih[g] + b_hh[g];     // bias row
            r[e] = (_Float16)(w * sc);
        }
    }
    return r;
}

// (320, 6 waves/EU) -> ~85-VGPR cap; 3-tile wave demand ~75 fits.
// NO global memory ops inside the T-loop: the __syncthreads vmcnt drain
// (R10-R18's hidden per-step serial HBM latency) is eliminated.
__global__ __launch_bounds__(NTHR_, 6)
void lstm_mfma(const float* __restrict__ x,
               const float* __restrict__ W_ih,
               const float* __restrict__ W_hh,
               const float* __restrict__ b_ih,
               const float* __restrict__ b_hh,
               const float* __restrict__ W_fc,
               const float* __restrict__ b_fc,
               float* __restrict__ out)
{
    extern __shared__ _Float16 dyn[];
    _Float16* xall = dyn;                 // [t][batch][16 feats]
    _Float16* st0  = dyn + XALL_;         // state buf 0: [batch][KP_]
    _Float16* st1  = st0 + STSZ_;         // state buf 1

    const int tid  = threadIdx.x;
    const int lane = tid & 63;
    const int wv   = tid >> 6;            // 0..4
    const int b0   = blockIdx.x * BPB_;

    // ---- init state: zeros; half 50 of each batch row = 1.0 (bias), pads 0
    for (int idx = tid; idx < 2 * BPB_ * KPW_; idx += NTHR_)
        ((u32*)st0)[idx] = ((idx % KPW_) == 25) ? 0x00003C00u : 0u;

    // ---- stage ALL x -> LDS fp16 (one time, coalesced float4 reads)
    for (int idx = tid; idx < T_ * BPB_ * 4; idx += NTHR_) {
        const int tt = idx >> 6;          // t
        const int bb = (idx >> 2) & 15;   // batch
        const int fq = idx & 3;           // feature quad
        const float4 v = *(const float4*)(x + (size_t)(b0 + bb) * (T_ * IN_)
                                            + (size_t)tt * IN_ + fq * 4);
        u32* d = (u32*)(xall + tt * XT_ + bb * 16 + fq * 4);
        d[0] = pkh2(v.x, v.y);
        d[1] = pkh2(v.z, v.w);
    }

    // ---- wave -> tiles {3,3,3,2,2}: start 0,3,6,9,11
    const int nt    = (wv < 3) ? 3 : 2;
    const int tile0 = (wv < 3) ? 3 * wv : 9 + 2 * (wv - 3);
    const int q     = lane >> 4;
    const int m     = lane & 15;
    const int bcol  = lane & 15;

    // ---- A-fragments from global -> regs (one time)
    const int s0 = tile0 * 16 + m;
    half8 A00 = load_afrag(W_ih, W_hh, b_ih, b_hh, s0,      0, q);
    half8 A01 = load_afrag(W_ih, W_hh, b_ih, b_hh, s0,      1, q);
    half8 A02 = load_afrag(W_ih, W_hh, b_ih, b_hh, s0,      2, q);
    half8 A10 = load_afrag(W_ih, W_hh, b_ih, b_hh, s0 + 16, 0, q);
    half8 A11 = load_afrag(W_ih, W_hh, b_ih, b_hh, s0 + 16, 1, q);
    half8 A12 = load_afrag(W_ih, W_hh, b_ih, b_hh, s0 + 16, 2, q);
    half8 A20 = {}, A21 = {}, A22 = {};
    if (nt == 3) {
        A20 = load_afrag(W_ih, W_hh, b_ih, b_hh, s0 + 32, 0, q);
        A21 = load_afrag(W_ih, W_hh, b_ih, b_hh, s0 + 32, 1, q);
        A22 = load_afrag(W_ih, W_hh, b_ih, b_hh, s0 + 32, 2, q);
    }

    // per-lane units (C/D: col=lane&15, row=q*4+reg -> unit = tile*4+q)
    const int u0 = (tile0    ) * 4 + q;
    const int u1 = (tile0 + 1) * 4 + q;
    const int u2 = (tile0 + 2) * 4 + q;
    float c0_ = 0.f, c1_ = 0.f, c2_ = 0.f;

    const int hrow0 = bcol * KP_ + u0;
    const int hrow1 = bcol * KP_ + u1;
    const int hrow2 = bcol * KP_ + u2;

    // B-fragment addressing (per-lane constants):
    //   B0: q<2 -> x_all[t] feats q*8..; q>=2 -> h rows (q-2)*8..
    //   B1: h rows 16+q*8 ; B2: q==0 -> rows 48..55 (h48,h49,bias,0*5), else zeros
    const bool isx  = (q < 2);
    const int xoff  = bcol * 16 + q * 8;
    const int b0off = bcol * KP_ + (q - 2) * 8;
    const int b1off = bcol * KP_ + 16 + q * 8;
    const int b2off = bcol * KP_ + ((q == 0) ? 48 : 56);

    __syncthreads();                      // staging + init visible

    for (int t = 0; t < T_; ++t) {
        const _Float16* sc = (t & 1) ? st1 : st0;
        _Float16*       sn = (t & 1) ? st0 : st1;

        const _Float16* pB0 = isx ? (xall + t * XT_ + xoff) : (sc + b0off);
        const half8 B0 = *(const half8*)pB0;
        const half8 B1 = *(const half8*)(sc + b1off);
        const half8 B2 = *(const half8*)(sc + b2off);
        const f32x4 Z = {0.f, 0.f, 0.f, 0.f};

        // 3 independent C-chains (chain 2 garbage for 2-tile waves; not written)
        f32x4 C0 = MFMA(A00, B0, Z);
        f32x4 C1 = MFMA(A10, B0, Z);
        f32x4 C2 = MFMA(A20, B0, Z);
        C0 = MFMA(A01, B1, C0);
        C1 = MFMA(A11, B1, C1);
        C2 = MFMA(A21, B1, C2);
        C0 = MFMA(A02, B2, C0);           // chunk 2 carries h-tails + bias row
        C1 = MFMA(A12, B2, C1);
        C2 = MFMA(A22, B2, C2);

        {   const float iv = SIGS(C0[0]), fv = SIGS(C0[1]);
            const float gv = TANHS(C0[2]), ov = SIGS(C0[3]);
            c0_ = fmaf(fv, c0_, iv * gv);
            if (u0 < HID_) sn[hrow0] = (_Float16)(ov * TANHS(c0_ * (-2.0f * L2E_))); }
        {   const float iv = SIGS(C1[0]), fv = SIGS(C1[1]);
            const float gv = TANHS(C1[2]), ov = SIGS(C1[3]);
            c1_ = fmaf(fv, c1_, iv * gv);
            if (u1 < HID_) sn[hrow1] = (_Float16)(ov * TANHS(c1_ * (-2.0f * L2E_))); }
        {   const float iv = SIGS(C2[0]), fv = SIGS(C2[1]);
            const float gv = TANHS(C2[2]), ov = SIGS(C2[3]);
            c2_ = fmaf(fv, c2_, iv * gv);
            if (nt == 3 && u2 < HID_)
                sn[hrow2] = (_Float16)(ov * TANHS(c2_ * (-2.0f * L2E_))); }

        __syncthreads();                  // ONE barrier/step; no vmcnt to drain
    }

    // final h in st0 (t=127 wrote buffer 0), fp16 rows 0..49
    // ---- FC head: 16 batches x 20 classes = 320 threads (exact)
    {
        const int b  = tid / NCLS_;
        const int cl = tid - b * NCLS_;
        const _Float16* hf = st0 + b * KP_;
        float acc = b_fc[cl];
        #pragma unroll
        for (int j = 0; j < HID_; ++j) {
            const float hv = fmaxf((float)hf[j], 0.0f);   // relu
            acc = fmaf(hv, W_fc[cl * HID_ + j], acc);
        }
        out[(size_t)(b0 + b) * NCLS_ + cl] = acc;
    }
}

extern "C" void kernel_launch(void* const* d_in, const int* in_sizes, int n_in,
                              void* d_out, int out_size, void* d_ws, size_t ws_size,
                              hipStream_t stream) {
    const float* x    = (const float*)d_in[0];
    const float* W_ih = (const float*)d_in[1];
    const float* W_hh = (const float*)d_in[2];
    const float* b_ih = (const float*)d_in[3];
    const float* b_hh = (const float*)d_in[4];
    const float* W_fc = (const float*)d_in[5];
    const float* b_fc = (const float*)d_in[6];
    float* out = (float*)d_out;

    // allow >64KB dynamic LDS (70144 B); idempotent, graph-capture-safe
    static bool attr_set = false;
    if (!attr_set) {
        hipFuncSetAttribute(reinterpret_cast<const void*>(lstm_mfma),
                            hipFuncAttributeMaxDynamicSharedMemorySize, LDSB_);
        attr_set = true;
    }

    const int B = in_sizes[0] / (T_ * IN_);   // 8192
    dim3 grid(B / BPB_), block(NTHR_);
    hipLaunchKernelGGL(lstm_mfma, grid, block, LDSB_, stream,
                       x, W_ih, W_hh, b_ih, b_hh, W_fc, b_fc, out);
}